// Round 1
// baseline (466.524 us; speedup 1.0000x reference)
//
#include <hip/hip_runtime.h>
#include <hip/hip_bf16.h>

#define S_ 128
#define R_ 384
#define D_ 256
#define DP_ 128
#define H_ 8
#define HD_ 32

typedef __attribute__((ext_vector_type(8))) short short8;
typedef __attribute__((ext_vector_type(4))) float f32x4;

__device__ __forceinline__ unsigned short f2bf(float f) {
    unsigned u = __builtin_bit_cast(unsigned, f);
    u = u + 0x7FFFu + ((u >> 16) & 1u);
    return (unsigned short)(u >> 16);
}
__device__ __forceinline__ float bf2f(unsigned short h) {
    unsigned u = ((unsigned)h) << 16;
    return __builtin_bit_cast(float, u);
}

// ---------------------------------------------------------------- weights->bf16
__global__ __launch_bounds__(256) void wconv_kernel(
    const float* __restrict__ Wq, const float* __restrict__ Wk,
    const float* __restrict__ Wv, const float* __restrict__ Wg,
    const float* __restrict__ Wo,
    unsigned short* __restrict__ wcat, unsigned short* __restrict__ wo)
{
    int i = blockIdx.x * 256 + threadIdx.x;   // grid covers 1024*256
    int rowblk = i >> 16;
    const float* src = (rowblk == 0) ? Wq : (rowblk == 1) ? Wk : (rowblk == 2) ? Wv : Wg;
    wcat[i] = f2bf(src[i & 65535]);
    if (i < 256 * 256) wo[i] = f2bf(Wo[i]);
}

// ------------------------------------------------- pair LN + bias = z_n @ Wz^T
// wave per (q,k) pair; 128 d_pair elems = 64 lanes x 2
__global__ __launch_bounds__(256) void bias_kernel(
    const float* __restrict__ z, const float* __restrict__ lnw,
    const float* __restrict__ lnb, const float* __restrict__ Wz,
    unsigned short* __restrict__ bias)
{
    const int lane = threadIdx.x & 63;
    const int w = threadIdx.x >> 6;
    const int p = blockIdx.x * 4 + w;
    const int q = p / R_;
    const int kk = p - q * R_;
    const float2 zv = *(const float2*)(z + (size_t)(q * R_ + kk) * DP_ + lane * 2);
    float s1 = zv.x + zv.y;
    float s2 = zv.x * zv.x + zv.y * zv.y;
#pragma unroll
    for (int t = 32; t >= 1; t >>= 1) { s1 += __shfl_xor(s1, t); s2 += __shfl_xor(s2, t); }
    const float mu = s1 * (1.0f / DP_);
    const float rstd = rsqrtf(s2 * (1.0f / DP_) - mu * mu + 1e-5f);
    const int d0 = lane * 2;
    const float zn0 = (zv.x - mu) * rstd * lnw[d0] + lnb[d0];
    const float zn1 = (zv.y - mu) * rstd * lnw[d0 + 1] + lnb[d0 + 1];
    float res[H_];
#pragma unroll
    for (int h = 0; h < H_; h++) {
        float pa = zn0 * Wz[h * DP_ + d0] + zn1 * Wz[h * DP_ + d0 + 1];
#pragma unroll
        for (int t = 32; t >= 1; t >>= 1) pa += __shfl_xor(pa, t);
        res[h] = pa;
    }
    if (lane == 0) {
#pragma unroll
        for (int h = 0; h < H_; h++)
            bias[((size_t)h * R_ + q) * R_ + kk] = f2bf(res[h]);
    }
}

// ---------------------------------------------------------------- MSA layernorm
__global__ __launch_bounds__(256) void lnm_kernel(
    const float* __restrict__ m, const float* __restrict__ lnw,
    const float* __restrict__ lnb, unsigned short* __restrict__ mn)
{
    const int lane = threadIdx.x & 63;
    const int w = threadIdx.x >> 6;
    const size_t row = (size_t)blockIdx.x * 4 + w;
    const float4 v = *(const float4*)(m + row * D_ + lane * 4);
    float s1 = v.x + v.y + v.z + v.w;
    float s2 = v.x * v.x + v.y * v.y + v.z * v.z + v.w * v.w;
#pragma unroll
    for (int t = 32; t >= 1; t >>= 1) { s1 += __shfl_xor(s1, t); s2 += __shfl_xor(s2, t); }
    const float mu = s1 * (1.0f / D_);
    const float rstd = rsqrtf(s2 * (1.0f / D_) - mu * mu + 1e-5f);
    const int d0 = lane * 4;
    ushort4 o;
    o.x = f2bf((v.x - mu) * rstd * lnw[d0 + 0] + lnb[d0 + 0]);
    o.y = f2bf((v.y - mu) * rstd * lnw[d0 + 1] + lnb[d0 + 1]);
    o.z = f2bf((v.z - mu) * rstd * lnw[d0 + 2] + lnb[d0 + 2]);
    o.w = f2bf((v.w - mu) * rstd * lnw[d0 + 3] + lnb[d0 + 3]);
    *(ushort4*)(mn + row * D_ + d0) = o;
}

// ------------------------------------------------------------------- MFMA GEMM
// C[M x N] = X[M x 256] * W[N x 256]^T ; BM=64 BN=64 BK=32, 4 waves.
// EPI 0: N=1024 fused epilogue -> q(scaled)/k/vt(transposed)/g(sigmoid) bf16
// EPI 1: N=256 plain f32 store
template <int EPI>
__global__ __launch_bounds__(256) void gemm_kernel(
    const unsigned short* __restrict__ X, const unsigned short* __restrict__ W,
    const float* __restrict__ bg,
    unsigned short* __restrict__ outq, unsigned short* __restrict__ outk,
    unsigned short* __restrict__ outvt, unsigned short* __restrict__ outg,
    float* __restrict__ outf)
{
    __shared__ unsigned short As[64][40];
    __shared__ unsigned short Ws[64][40];
    const int tid = threadIdx.x;
    const int lane = tid & 63;
    const int w = tid >> 6;
    const int m0 = blockIdx.x * 64;
    const int n0 = blockIdx.y * 64;
    const int ldr = tid >> 2;
    const int ldc = (tid & 3) * 8;
    const int rg = lane >> 4;
    const int cl = lane & 15;
    f32x4 acc[4];
#pragma unroll
    for (int i = 0; i < 4; i++) {
#pragma unroll
        for (int j = 0; j < 4; j++) acc[i][j] = 0.0f;
    }
    for (int k0 = 0; k0 < 256; k0 += 32) {
        const short8 av = *(const short8*)(X + (size_t)(m0 + ldr) * 256 + k0 + ldc);
        const short8 wv = *(const short8*)(W + (size_t)(n0 + ldr) * 256 + k0 + ldc);
        __syncthreads();
        *(short8*)(&As[ldr][ldc]) = av;
        *(short8*)(&Ws[ldr][ldc]) = wv;
        __syncthreads();
        const short8 af = *(const short8*)(&As[w * 16 + cl][rg * 8]);
#pragma unroll
        for (int sub = 0; sub < 4; sub++) {
            const short8 bf = *(const short8*)(&Ws[sub * 16 + cl][rg * 8]);
            acc[sub] = __builtin_amdgcn_mfma_f32_16x16x32_bf16(af, bf, acc[sub], 0, 0, 0);
        }
    }
#pragma unroll
    for (int sub = 0; sub < 4; sub++) {
        const int col = n0 + sub * 16 + cl;
#pragma unroll
        for (int ri = 0; ri < 4; ri++) {
            const int gr = m0 + w * 16 + rg * 4 + ri;
            const float val = acc[sub][ri];
            if constexpr (EPI == 0) {
                const int cat = col >> 8;
                const int el = col & 255;
                const int s = gr / R_;
                const int r = gr - s * R_;
                const int h = el >> 5;
                const int j = el & 31;
                const size_t hidx = (((size_t)s * H_ + h) * R_ + r) * HD_ + j;
                if (cat == 0) outq[hidx] = f2bf(val * 0.17677669529663687f);
                else if (cat == 1) outk[hidx] = f2bf(val);
                else if (cat == 2) outvt[(((size_t)s * H_ + h) * HD_ + j) * R_ + r] = f2bf(val);
                else {
                    const float sg = 1.0f / (1.0f + __expf(-(val + bg[el])));
                    outg[(size_t)gr * 256 + el] = f2bf(sg);
                }
            } else {
                outf[(size_t)gr * 256 + col] = val;
            }
        }
    }
}

// ------------------------------------------------------------------- attention
// grid (s=128, h=8, qblk=6); 4 waves, each owns 16 q rows. S in registers,
// softmax via shfl_xor in 16-lane groups, P through LDS to re-layout for PV.
__global__ __launch_bounds__(256) void attn_kernel(
    const unsigned short* __restrict__ Q, const unsigned short* __restrict__ K,
    const unsigned short* __restrict__ VT, const unsigned short* __restrict__ G,
    const unsigned short* __restrict__ bias, const float* __restrict__ mask,
    unsigned short* __restrict__ O)
{
    __shared__ unsigned short P[4][16][392];
    const int lane = threadIdx.x & 63;
    const int w = threadIdx.x >> 6;
    const int s = blockIdx.x;
    const int h = blockIdx.y;
    const int qbase = blockIdx.z * 64 + w * 16;
    const int rg = lane >> 4;
    const int cl = lane & 15;
    const size_t base = ((size_t)s * H_ + h) * R_ * HD_;
    const unsigned short* qp = Q + base;
    const unsigned short* kp = K + base;
    const unsigned short* vp = VT + base;  // same size: [32][384] per (s,h)
    const short8 qf = *(const short8*)(qp + (qbase + cl) * HD_ + rg * 8);
    f32x4 sv[24];
#pragma unroll
    for (int ct = 0; ct < 24; ct++) {
        const short8 kf = *(const short8*)(kp + (ct * 16 + cl) * HD_ + rg * 8);
        f32x4 zz; zz[0] = 0.f; zz[1] = 0.f; zz[2] = 0.f; zz[3] = 0.f;
        sv[ct] = __builtin_amdgcn_mfma_f32_16x16x32_bf16(qf, kf, zz, 0, 0, 0);
    }
    const float* mrow = mask + (size_t)s * R_;
#pragma unroll
    for (int ri = 0; ri < 4; ri++) {
        const int qrow = qbase + rg * 4 + ri;
        const unsigned short* brow = bias + ((size_t)h * R_ + qrow) * R_;
        float mx = -1e30f;
#pragma unroll
        for (int ct = 0; ct < 24; ct++) {
            const float t = sv[ct][ri] + bf2f(brow[ct * 16 + cl]) + mrow[ct * 16 + cl];
            sv[ct][ri] = t;
            mx = fmaxf(mx, t);
        }
        mx = fmaxf(mx, __shfl_xor(mx, 1));
        mx = fmaxf(mx, __shfl_xor(mx, 2));
        mx = fmaxf(mx, __shfl_xor(mx, 4));
        mx = fmaxf(mx, __shfl_xor(mx, 8));
        float sum = 0.f;
#pragma unroll
        for (int ct = 0; ct < 24; ct++) {
            const float e = __expf(sv[ct][ri] - mx);
            sv[ct][ri] = e;
            sum += e;
        }
        sum += __shfl_xor(sum, 1);
        sum += __shfl_xor(sum, 2);
        sum += __shfl_xor(sum, 4);
        sum += __shfl_xor(sum, 8);
        const float inv = 1.0f / sum;
#pragma unroll
        for (int ct = 0; ct < 24; ct++)
            P[w][rg * 4 + ri][ct * 16 + cl] = f2bf(sv[ct][ri] * inv);
    }
    __syncthreads();
    f32x4 oacc[2];
#pragma unroll
    for (int i = 0; i < 2; i++) {
#pragma unroll
        for (int j = 0; j < 4; j++) oacc[i][j] = 0.0f;
    }
#pragma unroll
    for (int kt = 0; kt < 12; kt++) {
        const short8 pf = *(const short8*)(&P[w][cl][kt * 32 + rg * 8]);
#pragma unroll
        for (int sub = 0; sub < 2; sub++) {
            const short8 vf = *(const short8*)(vp + (sub * 16 + cl) * R_ + kt * 32 + rg * 8);
            oacc[sub] = __builtin_amdgcn_mfma_f32_16x16x32_bf16(pf, vf, oacc[sub], 0, 0, 0);
        }
    }
#pragma unroll
    for (int sub = 0; sub < 2; sub++) {
        const int e = h * HD_ + sub * 16 + cl;
#pragma unroll
        for (int ri = 0; ri < 4; ri++) {
            const size_t gr = (size_t)s * R_ + qbase + rg * 4 + ri;
            const float gv = bf2f(G[gr * 256 + e]);
            O[gr * 256 + e] = f2bf(oacc[sub][ri] * gv);
        }
    }
}

// ------------------------------------------------------------------------ host
extern "C" void kernel_launch(void* const* d_in, const int* in_sizes, int n_in,
                              void* d_out, int out_size, void* d_ws, size_t ws_size,
                              hipStream_t stream)
{
    const float* m      = (const float*)d_in[0];
    const float* z      = (const float*)d_in[1];
    const float* mask   = (const float*)d_in[2];
    const float* ln_m_w = (const float*)d_in[3];
    const float* ln_m_b = (const float*)d_in[4];
    const float* ln_z_w = (const float*)d_in[5];
    const float* ln_z_b = (const float*)d_in[6];
    const float* Wz     = (const float*)d_in[7];
    const float* Wq     = (const float*)d_in[8];
    const float* Wk     = (const float*)d_in[9];
    const float* Wv     = (const float*)d_in[10];
    const float* Wg     = (const float*)d_in[11];
    const float* bg     = (const float*)d_in[12];
    const float* Wo     = (const float*)d_in[13];
    float* out = (float*)d_out;
    char* ws = (char*)d_ws;

    // ws layout (bytes)
    unsigned short* wbias = (unsigned short*)(ws);                         //  2,359,296
    unsigned short* wmn   = (unsigned short*)(ws + 2359296);               // 25,165,824 (reused as attn O)
    unsigned short* wq    = (unsigned short*)(ws + 27525120);              // 25,165,824
    unsigned short* wk    = (unsigned short*)(ws + 52690944);              // 25,165,824
    unsigned short* wvt   = (unsigned short*)(ws + 77856768);              // 25,165,824
    unsigned short* wg    = (unsigned short*)(ws + 103022592);             // 25,165,824
    unsigned short* wcat  = (unsigned short*)(ws + 128188416);             //    524,288
    unsigned short* wwo   = (unsigned short*)(ws + 128712704);             //    131,072

    wconv_kernel<<<1024, 256, 0, stream>>>(Wq, Wk, Wv, Wg, Wo, wcat, wwo);
    bias_kernel<<<36864, 256, 0, stream>>>(z, ln_z_w, ln_z_b, Wz, wbias);
    lnm_kernel<<<12288, 256, 0, stream>>>(m, ln_m_w, ln_m_b, wmn);
    gemm_kernel<0><<<dim3(768, 16), 256, 0, stream>>>(wmn, wcat, bg, wq, wk, wvt, wg, nullptr);
    attn_kernel<<<dim3(128, 8, 6), 256, 0, stream>>>(wq, wk, wvt, wg, wbias, mask, wmn);
    gemm_kernel<1><<<dim3(768, 4), 256, 0, stream>>>(wmn, wwo, nullptr, nullptr, nullptr, nullptr, nullptr, out);
}

// Round 2
// 391.746 us; speedup vs baseline: 1.1909x; 1.1909x over previous
//
#include <hip/hip_runtime.h>
#include <hip/hip_bf16.h>

#define S_ 128
#define R_ 384
#define D_ 256
#define DP_ 128
#define H_ 8
#define HD_ 32

typedef __attribute__((ext_vector_type(8))) short short8;
typedef __attribute__((ext_vector_type(4))) float f32x4;

__device__ __forceinline__ unsigned short f2bf(float f) {
    unsigned u = __builtin_bit_cast(unsigned, f);
    u = u + 0x7FFFu + ((u >> 16) & 1u);
    return (unsigned short)(u >> 16);
}
__device__ __forceinline__ float bf2f(unsigned short h) {
    unsigned u = ((unsigned)h) << 16;
    return __builtin_bit_cast(float, u);
}

// ---------------------------------------------------------------- weights->bf16
__global__ __launch_bounds__(256) void wconv_kernel(
    const float* __restrict__ Wq, const float* __restrict__ Wk,
    const float* __restrict__ Wv, const float* __restrict__ Wg,
    const float* __restrict__ Wo,
    unsigned short* __restrict__ wcat, unsigned short* __restrict__ wo)
{
    int i = blockIdx.x * 256 + threadIdx.x;   // grid covers 1024*256
    int rowblk = i >> 16;
    const float* src = (rowblk == 0) ? Wq : (rowblk == 1) ? Wk : (rowblk == 2) ? Wv : Wg;
    wcat[i] = f2bf(src[i & 65535]);
    if (i < 256 * 256) wo[i] = f2bf(Wo[i]);
}

// ------------------------------------------------- pair LN + bias = z_n @ Wz^T
// wave per (q,k) pair; output written in MFMA C-fragment layout:
// biasf[((h*24 + q/16)*24 + k/16)*256 + ((q%16)/4*16 + k%16)*4 + q%4]
__global__ __launch_bounds__(256) void bias_kernel(
    const float* __restrict__ z, const float* __restrict__ lnw,
    const float* __restrict__ lnb, const float* __restrict__ Wz,
    unsigned short* __restrict__ biasf)
{
    const int lane = threadIdx.x & 63;
    const int w = threadIdx.x >> 6;
    const int p = blockIdx.x * 4 + w;
    const int q = p / R_;
    const int kk = p - q * R_;
    const float2 zv = *(const float2*)(z + (size_t)(q * R_ + kk) * DP_ + lane * 2);
    float s1 = zv.x + zv.y;
    float s2 = zv.x * zv.x + zv.y * zv.y;
#pragma unroll
    for (int t = 32; t >= 1; t >>= 1) { s1 += __shfl_xor(s1, t); s2 += __shfl_xor(s2, t); }
    const float mu = s1 * (1.0f / DP_);
    const float rstd = rsqrtf(s2 * (1.0f / DP_) - mu * mu + 1e-5f);
    const int d0 = lane * 2;
    const float zn0 = (zv.x - mu) * rstd * lnw[d0] + lnb[d0];
    const float zn1 = (zv.y - mu) * rstd * lnw[d0 + 1] + lnb[d0 + 1];
    float res[H_];
#pragma unroll
    for (int h = 0; h < H_; h++) {
        float pa = zn0 * Wz[h * DP_ + d0] + zn1 * Wz[h * DP_ + d0 + 1];
#pragma unroll
        for (int t = 32; t >= 1; t >>= 1) pa += __shfl_xor(pa, t);
        res[h] = pa;
    }
    if (lane == 0) {
        const int qt = q >> 4, ct = kk >> 4;
        const int l = (((q & 15) >> 2) << 4) | (kk & 15);
        const int ri = q & 3;
        const size_t off = (size_t)(l * 4 + ri);
#pragma unroll
        for (int h = 0; h < H_; h++)
            biasf[(((size_t)(h * 24 + qt) * 24 + ct) << 8) + off] = f2bf(res[h]);
    }
}

// ---------------------------------------------------------------- MSA layernorm
__global__ __launch_bounds__(256) void lnm_kernel(
    const float* __restrict__ m, const float* __restrict__ lnw,
    const float* __restrict__ lnb, unsigned short* __restrict__ mn)
{
    const int lane = threadIdx.x & 63;
    const int w = threadIdx.x >> 6;
    const size_t row = (size_t)blockIdx.x * 4 + w;
    const float4 v = *(const float4*)(m + row * D_ + lane * 4);
    float s1 = v.x + v.y + v.z + v.w;
    float s2 = v.x * v.x + v.y * v.y + v.z * v.z + v.w * v.w;
#pragma unroll
    for (int t = 32; t >= 1; t >>= 1) { s1 += __shfl_xor(s1, t); s2 += __shfl_xor(s2, t); }
    const float mu = s1 * (1.0f / D_);
    const float rstd = rsqrtf(s2 * (1.0f / D_) - mu * mu + 1e-5f);
    const int d0 = lane * 4;
    ushort4 o;
    o.x = f2bf((v.x - mu) * rstd * lnw[d0 + 0] + lnb[d0 + 0]);
    o.y = f2bf((v.y - mu) * rstd * lnw[d0 + 1] + lnb[d0 + 1]);
    o.z = f2bf((v.z - mu) * rstd * lnw[d0 + 2] + lnb[d0 + 2]);
    o.w = f2bf((v.w - mu) * rstd * lnw[d0 + 3] + lnb[d0 + 3]);
    *(ushort4*)(mn + row * D_ + d0) = o;
}

// ------------------------------------------------------------------- MFMA GEMM
// C[M x N] = X[M x 256] * W[N x 256]^T ; BM=64 BN=64 BK=32, 4 waves.
// EPI 0: N=1024 fused epilogue -> q(scaled)/k/vt(transposed)/g(C-frag, sigmoid)
// EPI 1: N=256 plain f32 store
template <int EPI>
__global__ __launch_bounds__(256) void gemm_kernel(
    const unsigned short* __restrict__ X, const unsigned short* __restrict__ W,
    const float* __restrict__ bg,
    unsigned short* __restrict__ outq, unsigned short* __restrict__ outk,
    unsigned short* __restrict__ outvt, unsigned short* __restrict__ outg,
    float* __restrict__ outf)
{
    __shared__ unsigned short As[64][40];
    __shared__ unsigned short Ws[64][40];
    const int tid = threadIdx.x;
    const int lane = tid & 63;
    const int w = tid >> 6;
    const int m0 = blockIdx.x * 64;
    const int n0 = blockIdx.y * 64;
    const int ldr = tid >> 2;
    const int ldc = (tid & 3) * 8;
    const int rg = lane >> 4;
    const int cl = lane & 15;
    f32x4 acc[4];
#pragma unroll
    for (int i = 0; i < 4; i++) {
#pragma unroll
        for (int j = 0; j < 4; j++) acc[i][j] = 0.0f;
    }
    for (int k0 = 0; k0 < 256; k0 += 32) {
        const short8 av = *(const short8*)(X + (size_t)(m0 + ldr) * 256 + k0 + ldc);
        const short8 wv = *(const short8*)(W + (size_t)(n0 + ldr) * 256 + k0 + ldc);
        __syncthreads();
        *(short8*)(&As[ldr][ldc]) = av;
        *(short8*)(&Ws[ldr][ldc]) = wv;
        __syncthreads();
        const short8 af = *(const short8*)(&As[w * 16 + cl][rg * 8]);
#pragma unroll
        for (int sub = 0; sub < 4; sub++) {
            const short8 bf = *(const short8*)(&Ws[sub * 16 + cl][rg * 8]);
            acc[sub] = __builtin_amdgcn_mfma_f32_16x16x32_bf16(af, bf, acc[sub], 0, 0, 0);
        }
    }
#pragma unroll
    for (int sub = 0; sub < 4; sub++) {
        const int col = n0 + sub * 16 + cl;
#pragma unroll
        for (int ri = 0; ri < 4; ri++) {
            const int gr = m0 + w * 16 + rg * 4 + ri;
            const float val = acc[sub][ri];
            if constexpr (EPI == 0) {
                const int cat = col >> 8;
                const int el = col & 255;
                const int s = gr / R_;
                const int r = gr - s * R_;
                const int h = el >> 5;
                const int j = el & 31;
                const size_t hidx = (((size_t)s * H_ + h) * R_ + r) * HD_ + j;
                if (cat == 0) outq[hidx] = f2bf(val * 0.17677669529663687f);
                else if (cat == 1) outk[hidx] = f2bf(val);
                else if (cat == 2) outvt[(((size_t)s * H_ + h) * HD_ + j) * R_ + r] = f2bf(val);
                else {
                    const float sg = 1.0f / (1.0f + __expf(-(val + bg[el])));
                    // C-fragment layout: [s][h][qtile][sub&1][lane][ri]
                    outg[((((size_t)(s * 8 + h) * 24 + (r >> 4)) * 2 + (sub & 1)) << 8)
                         + (size_t)(rg * 16 + cl) * 4 + ri] = f2bf(sg);
                }
            } else {
                outf[(size_t)gr * 256 + col] = val;
            }
        }
    }
}

// ------------------------------------------------------------------- attention
// grid (s=128, h=8, z=6); 4 waves, each owns 16 q rows. S in registers,
// bias+mask folded into MFMA acc init; softmax via tree + shfl_xor in 16-lane
// groups; unnormalized P through per-wave LDS; 1/sum applied in epilogue.
__global__ __launch_bounds__(256) void attn_kernel(
    const unsigned short* __restrict__ Q, const unsigned short* __restrict__ K,
    const unsigned short* __restrict__ VT, const unsigned short* __restrict__ Gf,
    const unsigned short* __restrict__ biasf, const float* __restrict__ mask,
    unsigned short* __restrict__ O)
{
    __shared__ unsigned short P[4][16][386];
    __shared__ float mk[R_];
    const int tid = threadIdx.x;
    const int lane = tid & 63;
    const int w = tid >> 6;
    const int s = blockIdx.x;
    const int h = blockIdx.y;
    const int z = blockIdx.z;
    const int qbase = z * 64 + w * 16;
    const int qtile = z * 4 + w;
    const int rg = lane >> 4;
    const int cl = lane & 15;
    if (tid < 96)
        *(float4*)&mk[tid * 4] = *(const float4*)(mask + (size_t)s * R_ + tid * 4);
    __syncthreads();
    const size_t base = ((size_t)s * H_ + h) * (R_ * HD_);
    const short8 qf = *(const short8*)(Q + base + (qbase + cl) * HD_ + rg * 8);
    const unsigned short* bp = biasf + (((size_t)(h * 24 + qtile) * 24) << 8) + (size_t)lane * 4;
    f32x4 sv[24];
#pragma unroll
    for (int ct = 0; ct < 24; ct++) {
        const short8 kf = *(const short8*)(K + base + (ct * 16 + cl) * HD_ + rg * 8);
        const ushort4 bv = *(const ushort4*)(bp + ct * 256);
        const float mkv = mk[ct * 16 + cl];
        f32x4 ini;
        ini[0] = bf2f(bv.x) + mkv;
        ini[1] = bf2f(bv.y) + mkv;
        ini[2] = bf2f(bv.z) + mkv;
        ini[3] = bf2f(bv.w) + mkv;
        sv[ct] = __builtin_amdgcn_mfma_f32_16x16x32_bf16(qf, kf, ini, 0, 0, 0);
    }
    float inv[4];
#pragma unroll
    for (int ri = 0; ri < 4; ri++) {
        // tree max over 24 tiles (depth ~5)
        float x[12];
#pragma unroll
        for (int i = 0; i < 12; i++) x[i] = fmaxf(sv[2 * i][ri], sv[2 * i + 1][ri]);
#pragma unroll
        for (int i = 0; i < 6; i++) x[i] = fmaxf(x[i], x[i + 6]);
#pragma unroll
        for (int i = 0; i < 3; i++) x[i] = fmaxf(x[i], x[i + 3]);
        float mx = fmaxf(fmaxf(x[0], x[1]), x[2]);
        mx = fmaxf(mx, __shfl_xor(mx, 1));
        mx = fmaxf(mx, __shfl_xor(mx, 2));
        mx = fmaxf(mx, __shfl_xor(mx, 4));
        mx = fmaxf(mx, __shfl_xor(mx, 8));
        float sm[4] = {0.f, 0.f, 0.f, 0.f};
        unsigned short* prow = &P[w][rg * 4 + ri][0];
#pragma unroll
        for (int ct = 0; ct < 24; ct++) {
            const float e = __expf(sv[ct][ri] - mx);
            sm[ct & 3] += e;
            prow[ct * 16 + cl] = f2bf(e);
        }
        float sum = (sm[0] + sm[1]) + (sm[2] + sm[3]);
        sum += __shfl_xor(sum, 1);
        sum += __shfl_xor(sum, 2);
        sum += __shfl_xor(sum, 4);
        sum += __shfl_xor(sum, 8);
        inv[ri] = 1.0f / sum;
    }
    f32x4 oa[2][2];
#pragma unroll
    for (int i = 0; i < 2; i++)
#pragma unroll
        for (int p2 = 0; p2 < 2; p2++)
#pragma unroll
            for (int j = 0; j < 4; j++) oa[i][p2][j] = 0.0f;
#pragma unroll
    for (int kt = 0; kt < 12; kt++) {
        const short8 pf = *(const short8*)(&P[w][cl][kt * 32 + rg * 8]);
#pragma unroll
        for (int sub = 0; sub < 2; sub++) {
            const short8 vf = *(const short8*)(VT + base + (sub * 16 + cl) * R_ + kt * 32 + rg * 8);
            oa[sub][kt & 1] = __builtin_amdgcn_mfma_f32_16x16x32_bf16(pf, vf, oa[sub][kt & 1], 0, 0, 0);
        }
    }
    const unsigned short* gp = Gf + ((((size_t)(s * 8 + h) * 24 + qtile) * 2) << 8) + (size_t)lane * 4;
#pragma unroll
    for (int sub = 0; sub < 2; sub++) {
        const ushort4 gv = *(const ushort4*)(gp + sub * 256);
        const int e = h * HD_ + sub * 16 + cl;
        const float g0 = bf2f(gv.x), g1 = bf2f(gv.y), g2 = bf2f(gv.z), g3 = bf2f(gv.w);
#pragma unroll
        for (int ri = 0; ri < 4; ri++) {
            const size_t gr = (size_t)s * R_ + qbase + rg * 4 + ri;
            const float gg = (ri == 0) ? g0 : (ri == 1) ? g1 : (ri == 2) ? g2 : g3;
            const float o = (oa[sub][0][ri] + oa[sub][1][ri]) * inv[ri];
            O[gr * 256 + e] = f2bf(o * gg);
        }
    }
}

// ------------------------------------------------------------------------ host
extern "C" void kernel_launch(void* const* d_in, const int* in_sizes, int n_in,
                              void* d_out, int out_size, void* d_ws, size_t ws_size,
                              hipStream_t stream)
{
    const float* m      = (const float*)d_in[0];
    const float* z      = (const float*)d_in[1];
    const float* mask   = (const float*)d_in[2];
    const float* ln_m_w = (const float*)d_in[3];
    const float* ln_m_b = (const float*)d_in[4];
    const float* ln_z_w = (const float*)d_in[5];
    const float* ln_z_b = (const float*)d_in[6];
    const float* Wz     = (const float*)d_in[7];
    const float* Wq     = (const float*)d_in[8];
    const float* Wk     = (const float*)d_in[9];
    const float* Wv     = (const float*)d_in[10];
    const float* Wg     = (const float*)d_in[11];
    const float* bg     = (const float*)d_in[12];
    const float* Wo     = (const float*)d_in[13];
    float* out = (float*)d_out;
    char* ws = (char*)d_ws;

    // ws layout (bytes)
    unsigned short* wbias = (unsigned short*)(ws);                         //  2,359,296
    unsigned short* wmn   = (unsigned short*)(ws + 2359296);               // 25,165,824 (reused as attn O)
    unsigned short* wq    = (unsigned short*)(ws + 27525120);              // 25,165,824
    unsigned short* wk    = (unsigned short*)(ws + 52690944);              // 25,165,824
    unsigned short* wvt   = (unsigned short*)(ws + 77856768);              // 25,165,824
    unsigned short* wg    = (unsigned short*)(ws + 103022592);             // 25,165,824
    unsigned short* wcat  = (unsigned short*)(ws + 128188416);             //    524,288
    unsigned short* wwo   = (unsigned short*)(ws + 128712704);             //    131,072

    wconv_kernel<<<1024, 256, 0, stream>>>(Wq, Wk, Wv, Wg, Wo, wcat, wwo);
    bias_kernel<<<36864, 256, 0, stream>>>(z, ln_z_w, ln_z_b, Wz, wbias);
    lnm_kernel<<<12288, 256, 0, stream>>>(m, ln_m_w, ln_m_b, wmn);
    gemm_kernel<0><<<dim3(768, 16), 256, 0, stream>>>(wmn, wcat, bg, wq, wk, wvt, wg, nullptr);
    attn_kernel<<<dim3(128, 8, 6), 256, 0, stream>>>(wq, wk, wvt, wg, wbias, mask, wmn);
    gemm_kernel<1><<<dim3(768, 4), 256, 0, stream>>>(wmn, wwo, nullptr, nullptr, nullptr, nullptr, nullptr, out);
}